// Round 13
// baseline (254.297 us; speedup 1.0000x reference)
//
#include <hip/hip_runtime.h>

// Viterbi decoder forward: B=32, T=256, L=48, START=46, END=47.
// R13 = R11 + halved barrier count: EVEN steps use R11's split-partials ->
// s_barrier -> merge; ODD steps are computed redundantly per-wave fully
// in-register (48 readlane + 48 add + max tree), no barrier, no LDS.
// After a merge all waves hold identical vbest, so redundant steps stay
// consistent. Odd-step bp: value max tree on chain + first-occurrence
// descending equality scan (wave 0 only, off-chain). Emissions via R11's
// pinned register prefetch (issue 1 round ahead; "+v" pin at use; +tr
// fold under the barrier shadow). LSE identical structure in probability
// domain (P = E^T P, ldexp renorm). 127 barriers vs 254.

#define TT 256
#define LL 48
#define ROWF 2304          // 48*48 floats per time-row
#define LSTART 46
#define LEND 47
#define BB 32
#define LOG2E 1.44269504088896f
#define LN2 0.693147180559945f

#define RL(var, lane) __int_as_float(__builtin_amdgcn_readlane(__float_as_int(var), (lane)))

#define BARRIER() do { \
    asm volatile("s_waitcnt lgkmcnt(0)" ::: "memory"); \
    __builtin_amdgcn_s_barrier(); \
  } while (0)

// keep-alive pin (R11-proven): compiler emits its counted vmcnt wait here
#define PIN12(B) asm volatile("" : \
    "+v"((B)[0]), "+v"((B)[1]), "+v"((B)[2]),  "+v"((B)[3]), \
    "+v"((B)[4]), "+v"((B)[5]), "+v"((B)[6]),  "+v"((B)[7]), \
    "+v"((B)[8]), "+v"((B)[9]), "+v"((B)[10]), "+v"((B)[11]))
#define PIN48(B) do { PIN12(B); PIN12((B)+12); PIN12((B)+24); PIN12((B)+36); } while (0)

// plain loads (compiler-managed): 12-slice for even steps, full 48 for odd
#define LOADROW12(B, ROW) do { \
    const float* q_ = emB + (size_t)(ROW)*ROWF + (size_t)(12*w)*LL + jl; \
    _Pragma("unroll") \
    for (int k = 0; k < 12; ++k) (B)[k] = q_[k*LL]; \
  } while (0)
#define LOADROW48(B, ROW) do { \
    const float* q_ = emB + (size_t)(ROW)*ROWF + jl; \
    _Pragma("unroll") \
    for (int i = 0; i < 48; ++i) (B)[i] = q_[i*LL]; \
  } while (0)

// strict > with ordered pairing == jnp.argmax first-occurrence semantics
#define AMAX(vx, ix, vy, iy) do { if ((vy) > (vx)) { (vx)=(vy); (ix)=(iy);} } while(0)

// ---- odd (redundant) Viterbi step: cand in B48C (in place), all waves ----
#define ODD_V(B48C, T_) do { \
    _Pragma("unroll") \
    for (int i = 0; i < 48; ++i) (B48C)[i] += RL(vbest, i); \
    float mt_[16]; \
    _Pragma("unroll") \
    for (int i = 0; i < 16; ++i) \
      mt_[i] = fmaxf(fmaxf((B48C)[i], (B48C)[i+16]), (B48C)[i+32]); \
    _Pragma("unroll") \
    for (int i = 0; i < 8; ++i) mt_[i] = fmaxf(mt_[i], mt_[i+8]); \
    _Pragma("unroll") \
    for (int i = 0; i < 4; ++i) mt_[i] = fmaxf(mt_[i], mt_[i+4]); \
    float bv2_ = fmaxf(fmaxf(mt_[0], mt_[1]), fmaxf(mt_[2], mt_[3])); \
    const bool u2_ = act && ((T_) < len); \
    if (w == 0 && u2_) {  /* wave-uniform branch; first-occurrence scan */ \
      int id_ = 0; \
      _Pragma("unroll") \
      for (int i = 47; i >= 0; --i) if ((B48C)[i] == bv2_) id_ = i; \
      bp[(T_)*LL + j] = (unsigned char)id_; \
    } \
    vbest = u2_ ? bv2_ : vbest; \
  } while (0)

// ---- one Viterbi round: even step 2R (merge) + odd step 2R+1 (redundant)
#define ROUND_V(R_, B12C, B48C, B12N, B48N) do { \
    PIN12(B12C); \
    float etr_[12]; \
    _Pragma("unroll") \
    for (int k = 0; k < 12; ++k) etr_[k] = (B12C)[k] + trg12[k]; \
    float cv[12]; int ci[12]; \
    _Pragma("unroll") \
    for (int k = 0; k < 12; ++k) { \
      cv[k] = etr_[k] + RL(vbest, 12*w + k); ci[k] = 12*w + k; } \
    AMAX(cv[0],ci[0],cv[1],ci[1]);  AMAX(cv[2],ci[2],cv[3],ci[3]); \
    AMAX(cv[4],ci[4],cv[5],ci[5]);  AMAX(cv[6],ci[6],cv[7],ci[7]); \
    AMAX(cv[8],ci[8],cv[9],ci[9]);  AMAX(cv[10],ci[10],cv[11],ci[11]); \
    AMAX(cv[0],ci[0],cv[2],ci[2]);  AMAX(cv[4],ci[4],cv[6],ci[6]); \
    AMAX(cv[8],ci[8],cv[10],ci[10]); \
    AMAX(cv[0],ci[0],cv[4],ci[4]); \
    AMAX(cv[0],ci[0],cv[8],ci[8]); \
    partV[w][j] = make_float2(cv[0], __int_as_float(ci[0])); \
    { int rn_ = 2*(R_) + 2; if (rn_ > 255) rn_ = 255; LOADROW12(B12N, rn_); } \
    { int rn_ = 2*(R_) + 3; if (rn_ > 255) rn_ = 255; LOADROW48(B48N, rn_); } \
    PIN48(B48C); \
    _Pragma("unroll") \
    for (int i = 0; i < 48; ++i) (B48C)[i] += trg48[i]; \
    BARRIER(); \
    { \
      float2 m0_ = partV[0][j], m1_ = partV[1][j]; \
      float2 m2_ = partV[2][j], m3_ = partV[3][j]; \
      float bv_ = m0_.x; int ba_ = __float_as_int(m0_.y); \
      AMAX(bv_, ba_, m1_.x, __float_as_int(m1_.y)); \
      AMAX(bv_, ba_, m2_.x, __float_as_int(m2_.y)); \
      AMAX(bv_, ba_, m3_.x, __float_as_int(m3_.y)); \
      const bool u_ = act && (2*(R_) < len); \
      vbest = u_ ? bv_ : vbest; \
      if (w == 0 && u_) bp[2*(R_)*LL + j] = (unsigned char)ba_; \
    } \
    ODD_V(B48C, 2*(R_) + 1); \
  } while (0)

// ---- odd (redundant) LSE step: E in B48C, per-lane matvec + renorm ----
#define ODD_L(B48C, T_) do { \
    float a0_ = 0.f, a1_ = 0.f, a2_ = 0.f, a3_ = 0.f; \
    _Pragma("unroll") \
    for (int i = 0; i < 48; i += 4) { \
      a0_ = fmaf((B48C)[i+0], RL(P, i+0), a0_); \
      a1_ = fmaf((B48C)[i+1], RL(P, i+1), a1_); \
      a2_ = fmaf((B48C)[i+2], RL(P, i+2), a2_); \
      a3_ = fmaf((B48C)[i+3], RL(P, i+3), a3_); \
    } \
    float Pn_ = (a0_ + a1_) + (a2_ + a3_); \
    int rb_ = __builtin_amdgcn_readlane(__float_as_int(Pn_), 0); \
    int e_  = ((rb_ >> 23) & 255) - 127; \
    const bool u2_ = ((T_) < len); \
    P    = u2_ ? __builtin_ldexpf(Pn_, -e_) : P; \
    macc = u2_ ? macc + (float)e_ : macc; \
  } while (0)

#define ROUND_L(R_, B12C, B48C, B12N, B48N) do { \
    PIN12(B12C); \
    float ee_[12]; \
    _Pragma("unroll") \
    for (int k = 0; k < 12; ++k) ee_[k] = exp2f(fmaf((B12C)[k], LOG2E, trg12[k])); \
    { float a0_=0.f, a1_=0.f, a2_=0.f, a3_=0.f; \
      _Pragma("unroll") \
      for (int k = 0; k < 12; k += 4) { \
        a0_ = fmaf(ee_[k+0], RL(P, 12*w + k + 0), a0_); \
        a1_ = fmaf(ee_[k+1], RL(P, 12*w + k + 1), a1_); \
        a2_ = fmaf(ee_[k+2], RL(P, 12*w + k + 2), a2_); \
        a3_ = fmaf(ee_[k+3], RL(P, 12*w + k + 3), a3_); \
      } \
      partS[w][j] = (a0_ + a1_) + (a2_ + a3_); } \
    { int rn_ = 2*(R_) + 2; if (rn_ > 255) rn_ = 255; LOADROW12(B12N, rn_); } \
    { int rn_ = 2*(R_) + 3; if (rn_ > 255) rn_ = 255; LOADROW48(B48N, rn_); } \
    PIN48(B48C); \
    _Pragma("unroll") \
    for (int i = 0; i < 48; ++i) (B48C)[i] = exp2f(fmaf((B48C)[i], LOG2E, trg48[i])); \
    BARRIER(); \
    { \
      float Pn_ = (partS[0][j] + partS[1][j]) + (partS[2][j] + partS[3][j]); \
      int rb_ = __builtin_amdgcn_readlane(__float_as_int(Pn_), 0); \
      int e_  = ((rb_ >> 23) & 255) - 127; \
      const bool u_ = (2*(R_) < len); \
      P    = u_ ? __builtin_ldexpf(Pn_, -e_) : P; \
      macc = u_ ? macc + (float)e_ : macc; \
    } \
    ODD_L(B48C, 2*(R_) + 1); \
  } while (0)

__device__ __forceinline__ int load_len(const int* len_raw, int b) {
  // lengths int32-or-int64 detection (values 128..256)
  bool is64 = (len_raw[1] == 0) && (len_raw[3] == 0) && (len_raw[5] == 0);
  int len = is64 ? len_raw[2*b] : len_raw[b];
  if (len > TT) len = TT;
  if (len < 1) len = 1;
  return len;
}

__launch_bounds__(256, 1)
__global__ void viterbi_fwd(const float* __restrict__ em,
                            const float* __restrict__ tr,
                            const int* __restrict__ len_raw,
                            float* __restrict__ out,
                            float* __restrict__ ws)
{
  const int role = blockIdx.x >> 5;   // 0 = Viterbi, 1 = LSE
  const int b    = blockIdx.x & 31;
  const int tid  = threadIdx.x;
  const int w    = tid >> 6;
  const int j    = tid & 63;
  const bool act = (j < LL);
  const int jl   = act ? j : (LL - 1);
  const int len  = load_len(len_raw, b);

  __shared__ float2 partV[4][64];
  __shared__ float  partS[4][64];
  __shared__ unsigned char bp[TT*LL];
  __shared__ unsigned char cmp_[16*LL];
  __shared__ unsigned char entry_[16];
  __shared__ unsigned char raw[TT];

  const float* emB = em + (size_t)b*TT*ROWF;

  float trg48[48];
  #pragma unroll
  for (int i = 0; i < 48; ++i) trg48[i] = tr[i*LL + jl];

  if (role == 0) {
    // ===================== Viterbi =====================
    for (int idx = tid; idx < LL; idx += 256) bp[idx] = (unsigned char)LSTART;
    for (int idx = len*LL + tid; idx < TT*LL; idx += 256) bp[idx] = (unsigned char)LEND;
    __syncthreads();

    float trg12[12];
    #pragma unroll
    for (int k = 0; k < 12; ++k) trg12[k] = trg48[12*w + k];
    const float init = emB[LSTART*LL + jl] + trg48[LSTART];
    float vbest = act ? init : -INFINITY;

    float B12O[12], B12E[12], B48O[48], B48E[48];
    // prologue: row1 full (step 1), row2 slice (step 2), row3 full (step 3)
    LOADROW48(B48E, 1);
    LOADROW12(B12O, 2);
    LOADROW48(B48O, 3);
    // step 1 (redundant, no barrier)
    PIN48(B48E);
    #pragma unroll
    for (int i = 0; i < 48; ++i) B48E[i] += trg48[i];
    ODD_V(B48E, 1);

    // rounds r = 1..127 (steps 2..255); odd r uses O-buffers
    #pragma unroll 1
    for (int m = 0; m < 63; ++m) {
      ROUND_V(2*m + 1, B12O, B48O, B12E, B48E);
      ROUND_V(2*m + 2, B12E, B48E, B12O, B48O);
    }
    ROUND_V(127, B12O, B48O, B12E, B48E);

    if (tid == LEND) ws[BB + b] = vbest;  // best[END]
    __syncthreads();

    // ---- traceback, chunked (16 chunks x 16 steps) ----
    for (int idx = tid; idx < 16*LL; idx += 256) {
      int c = idx / LL, l = idx - c*LL;
      int pc = l;
      #pragma unroll
      for (int k = 15; k >= 0; --k) pc = bp[(16*c + k)*LL + pc];
      cmp_[c*LL + l] = (unsigned char)pc;
    }
    __syncthreads();
    if (tid == 0) {
      int pc = LEND;
      for (int c = 15; c >= 0; --c) { entry_[c] = (unsigned char)pc; pc = cmp_[c*LL + pc]; }
    }
    __syncthreads();
    if (tid < 16) {
      int c = tid, pc = entry_[c];
      #pragma unroll
      for (int k = 15; k >= 0; --k) { int t2 = 16*c + k; pc = bp[t2*LL + pc]; raw[t2] = (unsigned char)pc; }
    }
    __syncthreads();
    out[(size_t)b*TT + tid] = (tid < TT - 1) ? (float)raw[tid + 1] : (float)LEND;

  } else {
    // ===================== logsumexp (probability domain) =====================
    float trg12[12];
    #pragma unroll
    for (int k = 0; k < 12; ++k) trg12[k] = trg48[12*w + k] * LOG2E;
    #pragma unroll
    for (int i = 0; i < 48; ++i) trg48[i] *= LOG2E;

    const float init = emB[LSTART*LL + jl] + tr[LSTART*LL + jl];
    const float m2 = RL(init, 0) * LOG2E;
    float P = act ? exp2f(init * LOG2E - m2) : 0.f;
    float macc = m2;

    float B12O[12], B12E[12], B48O[48], B48E[48];
    LOADROW48(B48E, 1);
    LOADROW12(B12O, 2);
    LOADROW48(B48O, 3);
    // step 1 (redundant)
    PIN48(B48E);
    #pragma unroll
    for (int i = 0; i < 48; ++i) B48E[i] = exp2f(fmaf(B48E[i], LOG2E, trg48[i]));
    ODD_L(B48E, 1);

    #pragma unroll 1
    for (int m = 0; m < 63; ++m) {
      ROUND_L(2*m + 1, B12O, B48O, B12E, B48E);
      ROUND_L(2*m + 2, B12E, B48E, B12O, B48O);
    }
    ROUND_L(127, B12O, B48O, B12E, B48E);

    if (tid == LEND) ws[b] = (macc + __log2f(P)) * LN2;   // upto[END] in nats
  }
}

__global__ void viterbi_score(const float* __restrict__ ws, float* __restrict__ out)
{
  int b = threadIdx.x;
  if (b < BB) out[(size_t)BB*TT + b] = ws[BB + b] - ws[b];  // best - upto
}

extern "C" void kernel_launch(void* const* d_in, const int* in_sizes, int n_in,
                              void* d_out, int out_size, void* d_ws, size_t ws_size,
                              hipStream_t stream) {
  const float* em  = (const float*)d_in[0];
  const float* tr  = (const float*)d_in[1];
  const int*   ln  = (const int*)d_in[2];
  float* out = (float*)d_out;
  float* ws  = (float*)d_ws;
  viterbi_fwd<<<dim3(64), dim3(256), 0, stream>>>(em, tr, ln, out, ws);
  viterbi_score<<<dim3(1), dim3(64), 0, stream>>>(ws, out);
}

// Round 14
// 188.910 us; speedup vs baseline: 1.3461x; 1.3461x over previous
//
#include <hip/hip_runtime.h>

// Viterbi decoder forward: B=32, T=256, L=48, START=46, END=47.
// R14 = R11 with the LSE role FUSED into the Viterbi workgroups:
// 32 WGs, one batch each; per step ONE shared barrier; the Viterbi and
// LSE chains are independent between barriers so each fills the other's
// sync bubbles. One emission load feeds both (ee = exp2(etr*log2e),
// computed inline from V's etr -> no extra buffers). All components
// (pinned prefetch rotation, partials/merge parity, prob-domain LSE,
// traceback) are verbatim from R11 (121 us, passed).

#define TT 256
#define LL 48
#define ROWF 2304          // 48*48 floats per time-row
#define LSTART 46
#define LEND 47
#define BB 32
#define LOG2E 1.44269504088896f
#define LN2 0.693147180559945f

#define RL(var, lane) __int_as_float(__builtin_amdgcn_readlane(__float_as_int(var), (lane)))

#define BARRIER() do { \
    asm volatile("s_waitcnt lgkmcnt(0)" ::: "memory"); \
    __builtin_amdgcn_s_barrier(); \
  } while (0)

// keep-alive pin (R11-proven): compiler emits its counted vmcnt wait here
#define PIN12(B) asm volatile("" : \
    "+v"((B)[0]), "+v"((B)[1]), "+v"((B)[2]),  "+v"((B)[3]), \
    "+v"((B)[4]), "+v"((B)[5]), "+v"((B)[6]),  "+v"((B)[7]), \
    "+v"((B)[8]), "+v"((B)[9]), "+v"((B)[10]), "+v"((B)[11]))

// plain (compiler-managed) load of this lane's 12-element slice of ROW
#define LOADROW(B, ROW) do { \
    const float* q_ = emB + (size_t)(ROW)*ROWF + (size_t)(12*w)*LL + jl; \
    _Pragma("unroll") \
    for (int k = 0; k < 12; ++k) (B)[k] = q_[k*LL]; \
  } while (0)

// strict > with ordered pairing == jnp.argmax first-occurrence semantics
#define AMAX(vx, ix, vy, iy) do { if ((vy) > (vx)) { (vx)=(vy); (ix)=(iy);} } while(0)

// V partials of step PW-parity from ETR (row of that step)
#define PARTIALS_V(ETR, PW) do { \
    float cv[12]; int ci[12]; \
    _Pragma("unroll") \
    for (int k = 0; k < 12; ++k) { \
      cv[k] = (ETR)[k] + RL(vbest, 12*w + k); ci[k] = 12*w + k; } \
    AMAX(cv[0],ci[0],cv[1],ci[1]);  AMAX(cv[2],ci[2],cv[3],ci[3]); \
    AMAX(cv[4],ci[4],cv[5],ci[5]);  AMAX(cv[6],ci[6],cv[7],ci[7]); \
    AMAX(cv[8],ci[8],cv[9],ci[9]);  AMAX(cv[10],ci[10],cv[11],ci[11]); \
    AMAX(cv[0],ci[0],cv[2],ci[2]);  AMAX(cv[4],ci[4],cv[6],ci[6]); \
    AMAX(cv[8],ci[8],cv[10],ci[10]); \
    AMAX(cv[0],ci[0],cv[4],ci[4]); \
    AMAX(cv[0],ci[0],cv[8],ci[8]); \
    partV[PW][w][j] = make_float2(cv[0], __int_as_float(ci[0])); \
  } while (0)

// L partials of step PW-parity; ee derived inline from the same ETR
#define PARTIALS_L(ETR, PW) do { \
    float a0_ = 0.f, a1_ = 0.f, a2_ = 0.f, a3_ = 0.f; \
    _Pragma("unroll") \
    for (int k = 0; k < 12; k += 4) { \
      a0_ = fmaf(exp2f((ETR)[k+0]*LOG2E), RL(P, 12*w + k + 0), a0_); \
      a1_ = fmaf(exp2f((ETR)[k+1]*LOG2E), RL(P, 12*w + k + 1), a1_); \
      a2_ = fmaf(exp2f((ETR)[k+2]*LOG2E), RL(P, 12*w + k + 2), a2_); \
      a3_ = fmaf(exp2f((ETR)[k+3]*LOG2E), RL(P, 12*w + k + 3), a3_); \
    } \
    partS[PW][w][j] = (a0_ + a1_) + (a2_ + a3_); \
  } while (0)

// merge of step T_ (V: vbest/bp; L: P/macc renorm). Reads issued first.
#define MERGE_VL(T_, M0,M1,M2,M3, S0,S1,S2,S3) do { \
    float bv_ = (M0).x; int ba_ = __float_as_int((M0).y); \
    AMAX(bv_, ba_, (M1).x, __float_as_int((M1).y)); \
    AMAX(bv_, ba_, (M2).x, __float_as_int((M2).y)); \
    AMAX(bv_, ba_, (M3).x, __float_as_int((M3).y)); \
    const bool updv_ = act && ((T_) < len); \
    vbest = updv_ ? bv_ : vbest; \
    if (w == 0 && updv_) bp[(T_)*LL + j] = (unsigned char)ba_; \
    float Pn_ = ((S0) + (S1)) + ((S2) + (S3)); \
    int rb_ = __builtin_amdgcn_readlane(__float_as_int(Pn_), 0); \
    int e_  = ((rb_ >> 23) & 255) - 127; \
    const bool updl_ = ((T_) < len); \
    P    = updl_ ? __builtin_ldexpf(Pn_, -e_) : P; \
    macc = updl_ ? macc + (float)e_ : macc; \
  } while (0)

// fused iteration t: read merges (t-1), issue row t+3, pin row t+1,
// build next etr, merge both roles, partials both roles, one barrier.
#define ITER_VL(T_, BISS, BPIN, ETRC, ETRN) do { \
    const int pr_ = ((T_)-1) & 1; \
    float2 m0_ = partV[pr_][0][j], m1_ = partV[pr_][1][j]; \
    float2 m2_ = partV[pr_][2][j], m3_ = partV[pr_][3][j]; \
    float s0_ = partS[pr_][0][j], s1_ = partS[pr_][1][j]; \
    float s2_ = partS[pr_][2][j], s3_ = partS[pr_][3][j]; \
    { int row_ = (T_) + 3; if (row_ > 255) row_ = 255; LOADROW(BISS, row_); } \
    PIN12(BPIN); \
    _Pragma("unroll") \
    for (int k = 0; k < 12; ++k) (ETRN)[k] = (BPIN)[k] + trg[k]; \
    MERGE_VL((T_)-1, m0_,m1_,m2_,m3_, s0_,s1_,s2_,s3_); \
    PARTIALS_V(ETRC, (T_) & 1); \
    PARTIALS_L(ETRC, (T_) & 1); \
    BARRIER(); \
  } while (0)

__device__ __forceinline__ int load_len(const int* len_raw, int b) {
  // lengths int32-or-int64 detection (values 128..256)
  bool is64 = (len_raw[1] == 0) && (len_raw[3] == 0) && (len_raw[5] == 0);
  int len = is64 ? len_raw[2*b] : len_raw[b];
  if (len > TT) len = TT;
  if (len < 1) len = 1;
  return len;
}

__launch_bounds__(256, 1)
__global__ void viterbi_fwd(const float* __restrict__ em,
                            const float* __restrict__ tr,
                            const int* __restrict__ len_raw,
                            float* __restrict__ out,
                            float* __restrict__ ws)
{
  const int b    = blockIdx.x;        // one batch per WG (roles fused)
  const int tid  = threadIdx.x;
  const int w    = tid >> 6;
  const int j    = tid & 63;
  const bool act = (j < LL);
  const int jl   = act ? j : (LL - 1);
  const int len  = load_len(len_raw, b);

  __shared__ float2 partV[2][4][64];
  __shared__ float  partS[2][4][64];
  __shared__ unsigned char bp[TT*LL];
  __shared__ unsigned char cmp_[16*LL];
  __shared__ unsigned char entry_[16];
  __shared__ unsigned char raw[TT];

  const float* emB = em + (size_t)b*TT*ROWF;

  // bp boundary rows (disjoint from loop writes: rows [1,len) )
  for (int idx = tid; idx < LL; idx += 256) bp[idx] = (unsigned char)LSTART;
  for (int idx = len*LL + tid; idx < TT*LL; idx += 256) bp[idx] = (unsigned char)LEND;
  __syncthreads();

  float trg[12];
  #pragma unroll
  for (int k = 0; k < 12; ++k) trg[k] = tr[(12*w + k)*LL + jl];

  const float init = emB[LSTART*LL + jl] + tr[LSTART*LL + jl];
  float vbest = act ? init : -INFINITY;
  // LSE state: probability domain, P scaled by 2^-macc
  const float m2 = RL(init, 0) * LOG2E;
  float P = act ? exp2f(init * LOG2E - m2) : 0.f;
  float macc = m2;

  float B0[12], B1[12], B2[12], B3[12], etrA[12], etrB[12];
  // prologue: rows 1..3; partials of step 1 (both roles); row 4; etrA = row 2
  LOADROW(B1, 1); LOADROW(B2, 2); LOADROW(B3, 3);
  PIN12(B1);
  {
    float e1[12];
    #pragma unroll
    for (int k = 0; k < 12; ++k) e1[k] = B1[k] + trg[k];
    PARTIALS_V(e1, 1);
    PARTIALS_L(e1, 1);
  }
  LOADROW(B0, 4);
  PIN12(B2);
  #pragma unroll
  for (int k = 0; k < 12; ++k) etrA[k] = B2[k] + trg[k];
  BARRIER();

  // loop t = 2..253 (63 quad blocks), then peel 254, 255
  #pragma unroll 1
  for (int m = 0; m < 63; ++m) {
    const int t0 = 4*m + 2;
    ITER_VL(t0,     B1, B3, etrA, etrB);
    ITER_VL(t0 + 1, B2, B0, etrB, etrA);
    ITER_VL(t0 + 2, B3, B1, etrA, etrB);
    ITER_VL(t0 + 3, B0, B2, etrB, etrA);
  }
  // t=254: pin row 255 (B3), merge 253, publish 254
  {
    float2 m0_ = partV[1][0][j], m1_ = partV[1][1][j];
    float2 m2_ = partV[1][2][j], m3_ = partV[1][3][j];
    float s0_ = partS[1][0][j], s1_ = partS[1][1][j];
    float s2_ = partS[1][2][j], s3_ = partS[1][3][j];
    PIN12(B3);
    #pragma unroll
    for (int k = 0; k < 12; ++k) etrB[k] = B3[k] + trg[k];
    MERGE_VL(253, m0_,m1_,m2_,m3_, s0_,s1_,s2_,s3_);
    PARTIALS_V(etrA, 0);
    PARTIALS_L(etrA, 0);
    BARRIER();
  }
  // t=255: merge 254, publish 255
  {
    float2 m0_ = partV[0][0][j], m1_ = partV[0][1][j];
    float2 m2_ = partV[0][2][j], m3_ = partV[0][3][j];
    float s0_ = partS[0][0][j], s1_ = partS[0][1][j];
    float s2_ = partS[0][2][j], s3_ = partS[0][3][j];
    MERGE_VL(254, m0_,m1_,m2_,m3_, s0_,s1_,s2_,s3_);
    PARTIALS_V(etrB, 1);
    PARTIALS_L(etrB, 1);
    BARRIER();
  }
  // final merge of step 255
  {
    float2 m0_ = partV[1][0][j], m1_ = partV[1][1][j];
    float2 m2_ = partV[1][2][j], m3_ = partV[1][3][j];
    float s0_ = partS[1][0][j], s1_ = partS[1][1][j];
    float s2_ = partS[1][2][j], s3_ = partS[1][3][j];
    MERGE_VL(255, m0_,m1_,m2_,m3_, s0_,s1_,s2_,s3_);
  }

  if (tid == LEND) {
    ws[BB + b] = vbest;                       // best[END]
    ws[b] = (macc + __log2f(P)) * LN2;        // upto[END] in nats
  }
  __syncthreads();

  // ---- traceback, chunked (16 chunks x 16 steps) ----
  for (int idx = tid; idx < 16*LL; idx += 256) {
    int c = idx / LL, l = idx - c*LL;
    int pc = l;
    #pragma unroll
    for (int k = 15; k >= 0; --k) pc = bp[(16*c + k)*LL + pc];
    cmp_[c*LL + l] = (unsigned char)pc;
  }
  __syncthreads();
  if (tid == 0) {
    int pc = LEND;
    for (int c = 15; c >= 0; --c) { entry_[c] = (unsigned char)pc; pc = cmp_[c*LL + pc]; }
  }
  __syncthreads();
  if (tid < 16) {
    int c = tid, pc = entry_[c];
    #pragma unroll
    for (int k = 15; k >= 0; --k) { int t2 = 16*c + k; pc = bp[t2*LL + pc]; raw[t2] = (unsigned char)pc; }
  }
  __syncthreads();
  out[(size_t)b*TT + tid] = (tid < TT - 1) ? (float)raw[tid + 1] : (float)LEND;
}

__global__ void viterbi_score(const float* __restrict__ ws, float* __restrict__ out)
{
  int b = threadIdx.x;
  if (b < BB) out[(size_t)BB*TT + b] = ws[BB + b] - ws[b];  // best - upto
}

extern "C" void kernel_launch(void* const* d_in, const int* in_sizes, int n_in,
                              void* d_out, int out_size, void* d_ws, size_t ws_size,
                              hipStream_t stream) {
  const float* em  = (const float*)d_in[0];
  const float* tr  = (const float*)d_in[1];
  const int*   ln  = (const int*)d_in[2];
  float* out = (float*)d_out;
  float* ws  = (float*)d_ws;
  viterbi_fwd<<<dim3(32), dim3(256), 0, stream>>>(em, tr, ln, out, ws);
  viterbi_score<<<dim3(1), dim3(64), 0, stream>>>(ws, out);
}

// Round 15
// 125.681 us; speedup vs baseline: 2.0233x; 1.5031x over previous
//
#include <hip/hip_runtime.h>

// Viterbi decoder forward: B=32, T=256, L=48, START=46, END=47.
// R15 = R11 verbatim (best measured: 121 us kernel / 125.7 us total).
// Structure: 64 WGs (32 Viterbi + 32 LSE), 4 waves, 12 i's/wave, lane j =
// label; LDS partial merge with parity double-buffer; raw lgkm-only
// barrier (global prefetch never drained); pinned register prefetch
// (plain loads issued 3 rows ahead, "+v" empty-asm pin 2 rows ahead puts
// the compiler's counted vmcnt wait off the critical chain). LSE in
// probability domain: P = E^T P, ldexp renorm, single log2 at the end.

#define TT 256
#define LL 48
#define ROWF 2304          // 48*48 floats per time-row
#define LSTART 46
#define LEND 47
#define BB 32
#define LOG2E 1.44269504088896f
#define LN2 0.693147180559945f

#define RL(var, lane) __int_as_float(__builtin_amdgcn_readlane(__float_as_int(var), (lane)))

#define BARRIER() do { \
    asm volatile("s_waitcnt lgkmcnt(0)" ::: "memory"); \
    __builtin_amdgcn_s_barrier(); \
  } while (0)

// keep-alive pin: forces the 12 loaded values into live VGPRs HERE; the
// compiler inserts its own (counted) vmcnt wait before this point.
#define PIN12(B) asm volatile("" : \
    "+v"((B)[0]), "+v"((B)[1]), "+v"((B)[2]),  "+v"((B)[3]), \
    "+v"((B)[4]), "+v"((B)[5]), "+v"((B)[6]),  "+v"((B)[7]), \
    "+v"((B)[8]), "+v"((B)[9]), "+v"((B)[10]), "+v"((B)[11]))

// plain (compiler-managed) load of this lane's 12-element slice of ROW
#define LOADROW(B, ROW) do { \
    const float* q_ = emB + (size_t)(ROW)*ROWF + (size_t)(12*w)*LL + jl; \
    _Pragma("unroll") \
    for (int k = 0; k < 12; ++k) (B)[k] = q_[k*LL]; \
  } while (0)

// strict > with ordered pairing == jnp.argmax first-occurrence semantics
#define AMAX(vx, ix, vy, iy) do { if ((vy) > (vx)) { (vx)=(vy); (ix)=(iy);} } while(0)

// 12-candidate partial max/argmax tree -> partV[PW][w][j]
#define PARTIALS_V(ETR, PW) do { \
    float cv[12]; int ci[12]; \
    _Pragma("unroll") \
    for (int k = 0; k < 12; ++k) { \
      cv[k] = (ETR)[k] + RL(vbest, 12*w + k); ci[k] = 12*w + k; } \
    AMAX(cv[0],ci[0],cv[1],ci[1]);  AMAX(cv[2],ci[2],cv[3],ci[3]); \
    AMAX(cv[4],ci[4],cv[5],ci[5]);  AMAX(cv[6],ci[6],cv[7],ci[7]); \
    AMAX(cv[8],ci[8],cv[9],ci[9]);  AMAX(cv[10],ci[10],cv[11],ci[11]); \
    AMAX(cv[0],ci[0],cv[2],ci[2]);  AMAX(cv[4],ci[4],cv[6],ci[6]); \
    AMAX(cv[8],ci[8],cv[10],ci[10]); \
    AMAX(cv[0],ci[0],cv[4],ci[4]); \
    AMAX(cv[0],ci[0],cv[8],ci[8]); \
    partV[PW][w][j] = make_float2(cv[0], __int_as_float(ci[0])); \
  } while (0)

// Viterbi iteration t: merge step t-1, issue row t+3, pin row t+1 (build
// ETRN off-chain), chain-update vbest, partials of step t, barrier.
#define ITER_V(T_, BISS, BPIN, ETRC, ETRN) do { \
    const int pr_ = ((T_)-1) & 1; \
    float2 m0_ = partV[pr_][0][j], m1_ = partV[pr_][1][j]; \
    float2 m2_ = partV[pr_][2][j], m3_ = partV[pr_][3][j]; \
    { int row_ = (T_) + 3; if (row_ > 255) row_ = 255; LOADROW(BISS, row_); } \
    PIN12(BPIN); \
    _Pragma("unroll") \
    for (int k = 0; k < 12; ++k) (ETRN)[k] = (BPIN)[k] + trg[k]; \
    float bv_ = m0_.x; int ba_ = __float_as_int(m0_.y); \
    AMAX(bv_, ba_, m1_.x, __float_as_int(m1_.y)); \
    AMAX(bv_, ba_, m2_.x, __float_as_int(m2_.y)); \
    AMAX(bv_, ba_, m3_.x, __float_as_int(m3_.y)); \
    { const bool upd_ = act && (((T_)-1) < len); \
      vbest = upd_ ? bv_ : vbest; \
      if (w == 0 && upd_) bp[((T_)-1)*LL + j] = (unsigned char)ba_; } \
    PARTIALS_V(ETRC, (T_) & 1); \
    BARRIER(); \
  } while (0)

#define PARTIALS_L(EE, PW) do { \
    float a0 = 0.f, a1 = 0.f, a2 = 0.f, a3 = 0.f; \
    _Pragma("unroll") \
    for (int k = 0; k < 12; k += 4) { \
      a0 = fmaf((EE)[k+0], RL(P, 12*w + k + 0), a0); \
      a1 = fmaf((EE)[k+1], RL(P, 12*w + k + 1), a1); \
      a2 = fmaf((EE)[k+2], RL(P, 12*w + k + 2), a2); \
      a3 = fmaf((EE)[k+3], RL(P, 12*w + k + 3), a3); \
    } \
    partS[PW][w][j] = (a0 + a1) + (a2 + a3); \
  } while (0)

#define ITER_L(T_, BISS, BPIN, EEC, EEN) do { \
    const int pr_ = ((T_)-1) & 1; \
    float s0_ = partS[pr_][0][j], s1_ = partS[pr_][1][j]; \
    float s2_ = partS[pr_][2][j], s3_ = partS[pr_][3][j]; \
    { int row_ = (T_) + 3; if (row_ > 255) row_ = 255; LOADROW(BISS, row_); } \
    PIN12(BPIN); \
    _Pragma("unroll") \
    for (int k = 0; k < 12; ++k) \
      (EEN)[k] = exp2f(fmaf((BPIN)[k], LOG2E, trg2[k])); \
    float Pn_ = (s0_ + s1_) + (s2_ + s3_); \
    { int rb_ = __builtin_amdgcn_readlane(__float_as_int(Pn_), 0); \
      int e_ = ((rb_ >> 23) & 255) - 127; \
      const bool upd_ = (((T_)-1) < len); \
      P    = upd_ ? __builtin_ldexpf(Pn_, -e_) : P; \
      macc = upd_ ? macc + (float)e_ : macc; } \
    PARTIALS_L(EEC, (T_) & 1); \
    BARRIER(); \
  } while (0)

__device__ __forceinline__ int load_len(const int* len_raw, int b) {
  // lengths int32-or-int64 detection (values 128..256)
  bool is64 = (len_raw[1] == 0) && (len_raw[3] == 0) && (len_raw[5] == 0);
  int len = is64 ? len_raw[2*b] : len_raw[b];
  if (len > TT) len = TT;
  if (len < 1) len = 1;
  return len;
}

__launch_bounds__(256, 1)
__global__ void viterbi_fwd(const float* __restrict__ em,
                            const float* __restrict__ tr,
                            const int* __restrict__ len_raw,
                            float* __restrict__ out,
                            float* __restrict__ ws)
{
  const int role = blockIdx.x >> 5;   // 0 = Viterbi, 1 = LSE
  const int b    = blockIdx.x & 31;
  const int tid  = threadIdx.x;
  const int w    = tid >> 6;
  const int j    = tid & 63;
  const bool act = (j < LL);
  const int jl   = act ? j : (LL - 1);
  const int len  = load_len(len_raw, b);

  __shared__ float2 partV[2][4][64];
  __shared__ float  partS[2][4][64];
  __shared__ unsigned char bp[TT*LL];
  __shared__ unsigned char cmp_[16*LL];
  __shared__ unsigned char entry_[16];
  __shared__ unsigned char raw[TT];

  const float* emB = em + (size_t)b*TT*ROWF;

  if (role == 0) {
    // ===================== Viterbi =====================
    for (int idx = tid; idx < LL; idx += 256) bp[idx] = (unsigned char)LSTART;
    for (int idx = len*LL + tid; idx < TT*LL; idx += 256) bp[idx] = (unsigned char)LEND;
    __syncthreads();

    float trg[12];
    #pragma unroll
    for (int k = 0; k < 12; ++k) trg[k] = tr[(12*w + k)*LL + jl];
    const float init = emB[LSTART*LL + jl] + tr[LSTART*LL + jl];
    float vbest = act ? init : -INFINITY;

    float B0[12], B1[12], B2[12], B3[12], etrA[12], etrB[12];
    // prologue: rows 1..3; partials of step 1; row 4; etrA = row 2
    LOADROW(B1, 1); LOADROW(B2, 2); LOADROW(B3, 3);
    PIN12(B1);
    {
      float e1[12];
      #pragma unroll
      for (int k = 0; k < 12; ++k) e1[k] = B1[k] + trg[k];
      PARTIALS_V(e1, 1);
    }
    LOADROW(B0, 4);
    PIN12(B2);
    #pragma unroll
    for (int k = 0; k < 12; ++k) etrA[k] = B2[k] + trg[k];
    BARRIER();

    // loop t = 2..253 (63 quad blocks), then peel 254, 255
    #pragma unroll 1
    for (int m = 0; m < 63; ++m) {
      const int t0 = 4*m + 2;
      ITER_V(t0,     B1, B3, etrA, etrB);
      ITER_V(t0 + 1, B2, B0, etrB, etrA);
      ITER_V(t0 + 2, B3, B1, etrA, etrB);
      ITER_V(t0 + 3, B0, B2, etrB, etrA);
    }
    // t=254: no new issue needed; pin row 255 (in B3)
    {
      const int pr_ = 253 & 1;
      float2 m0_ = partV[pr_][0][j], m1_ = partV[pr_][1][j];
      float2 m2_ = partV[pr_][2][j], m3_ = partV[pr_][3][j];
      PIN12(B3);
      #pragma unroll
      for (int k = 0; k < 12; ++k) etrB[k] = B3[k] + trg[k];
      float bv_ = m0_.x; int ba_ = __float_as_int(m0_.y);
      AMAX(bv_, ba_, m1_.x, __float_as_int(m1_.y));
      AMAX(bv_, ba_, m2_.x, __float_as_int(m2_.y));
      AMAX(bv_, ba_, m3_.x, __float_as_int(m3_.y));
      const bool upd_ = act && (253 < len);
      vbest = upd_ ? bv_ : vbest;
      if (w == 0 && upd_) bp[253*LL + j] = (unsigned char)ba_;
      PARTIALS_V(etrA, 0);
      BARRIER();
    }
    // t=255
    {
      float2 m0_ = partV[0][0][j], m1_ = partV[0][1][j];
      float2 m2_ = partV[0][2][j], m3_ = partV[0][3][j];
      float bv_ = m0_.x; int ba_ = __float_as_int(m0_.y);
      AMAX(bv_, ba_, m1_.x, __float_as_int(m1_.y));
      AMAX(bv_, ba_, m2_.x, __float_as_int(m2_.y));
      AMAX(bv_, ba_, m3_.x, __float_as_int(m3_.y));
      const bool upd_ = act && (254 < len);
      vbest = upd_ ? bv_ : vbest;
      if (w == 0 && upd_) bp[254*LL + j] = (unsigned char)ba_;
      PARTIALS_V(etrB, 1);
      BARRIER();
    }
    // final merge: step 255 partials in partV[1]
    {
      float2 m0 = partV[1][0][j], m1 = partV[1][1][j];
      float2 m2 = partV[1][2][j], m3 = partV[1][3][j];
      float bv = m0.x; int ba = __float_as_int(m0.y);
      AMAX(bv, ba, m1.x, __float_as_int(m1.y));
      AMAX(bv, ba, m2.x, __float_as_int(m2.y));
      AMAX(bv, ba, m3.x, __float_as_int(m3.y));
      const bool upd = act && (255 < len);
      vbest = upd ? bv : vbest;
      if (w == 0 && upd) bp[255*LL + j] = (unsigned char)ba;
    }
    if (tid == LEND) ws[BB + b] = vbest;  // best[END]
    __syncthreads();

    // ---- traceback, chunked (16 chunks x 16 steps) ----
    for (int idx = tid; idx < 16*LL; idx += 256) {
      int c = idx / LL, l = idx - c*LL;
      int pc = l;
      #pragma unroll
      for (int k = 15; k >= 0; --k) pc = bp[(16*c + k)*LL + pc];
      cmp_[c*LL + l] = (unsigned char)pc;
    }
    __syncthreads();
    if (tid == 0) {
      int pc = LEND;
      for (int c = 15; c >= 0; --c) { entry_[c] = (unsigned char)pc; pc = cmp_[c*LL + pc]; }
    }
    __syncthreads();
    if (tid < 16) {
      int c = tid, pc = entry_[c];
      #pragma unroll
      for (int k = 15; k >= 0; --k) { int t2 = 16*c + k; pc = bp[t2*LL + pc]; raw[t2] = (unsigned char)pc; }
    }
    __syncthreads();
    out[(size_t)b*TT + tid] = (tid < TT - 1) ? (float)raw[tid + 1] : (float)LEND;

  } else {
    // ===================== logsumexp (probability domain) =====================
    float trg2[12];
    #pragma unroll
    for (int k = 0; k < 12; ++k) trg2[k] = tr[(12*w + k)*LL + jl] * LOG2E;
    const float init = emB[LSTART*LL + jl] + tr[LSTART*LL + jl];
    const float m2 = RL(init, 0) * LOG2E;
    float P = act ? exp2f(init * LOG2E - m2) : 0.f;
    float macc = m2;

    float B0[12], B1[12], B2[12], B3[12], eeA[12], eeB[12];
    LOADROW(B1, 1); LOADROW(B2, 2); LOADROW(B3, 3);
    PIN12(B1);
    {
      float e1[12];
      #pragma unroll
      for (int k = 0; k < 12; ++k) e1[k] = exp2f(fmaf(B1[k], LOG2E, trg2[k]));
      PARTIALS_L(e1, 1);
    }
    LOADROW(B0, 4);
    PIN12(B2);
    #pragma unroll
    for (int k = 0; k < 12; ++k) eeA[k] = exp2f(fmaf(B2[k], LOG2E, trg2[k]));
    BARRIER();

    #pragma unroll 1
    for (int m = 0; m < 63; ++m) {
      const int t0 = 4*m + 2;
      ITER_L(t0,     B1, B3, eeA, eeB);
      ITER_L(t0 + 1, B2, B0, eeB, eeA);
      ITER_L(t0 + 2, B3, B1, eeA, eeB);
      ITER_L(t0 + 3, B0, B2, eeB, eeA);
    }
    // t=254
    {
      const int pr_ = 253 & 1;
      float s0_ = partS[pr_][0][j], s1_ = partS[pr_][1][j];
      float s2_ = partS[pr_][2][j], s3_ = partS[pr_][3][j];
      PIN12(B3);
      #pragma unroll
      for (int k = 0; k < 12; ++k) eeB[k] = exp2f(fmaf(B3[k], LOG2E, trg2[k]));
      float Pn_ = (s0_ + s1_) + (s2_ + s3_);
      int rb_ = __builtin_amdgcn_readlane(__float_as_int(Pn_), 0);
      int e_ = ((rb_ >> 23) & 255) - 127;
      const bool upd_ = (253 < len);
      P    = upd_ ? __builtin_ldexpf(Pn_, -e_) : P;
      macc = upd_ ? macc + (float)e_ : macc;
      PARTIALS_L(eeA, 0);
      BARRIER();
    }
    // t=255
    {
      float s0_ = partS[0][0][j], s1_ = partS[0][1][j];
      float s2_ = partS[0][2][j], s3_ = partS[0][3][j];
      float Pn_ = (s0_ + s1_) + (s2_ + s3_);
      int rb_ = __builtin_amdgcn_readlane(__float_as_int(Pn_), 0);
      int e_ = ((rb_ >> 23) & 255) - 127;
      const bool upd_ = (254 < len);
      P    = upd_ ? __builtin_ldexpf(Pn_, -e_) : P;
      macc = upd_ ? macc + (float)e_ : macc;
      PARTIALS_L(eeB, 1);
      BARRIER();
    }
    // final merge: step 255
    {
      float Pn = (partS[1][0][j] + partS[1][1][j])
               + (partS[1][2][j] + partS[1][3][j]);
      int rb = __builtin_amdgcn_readlane(__float_as_int(Pn), 0);
      int e  = ((rb >> 23) & 255) - 127;
      const bool upd = (255 < len);
      P    = upd ? __builtin_ldexpf(Pn, -e) : P;
      macc = upd ? macc + (float)e : macc;
    }
    if (tid == LEND) ws[b] = (macc + __log2f(P)) * LN2;   // upto[END] in nats
  }
}

__global__ void viterbi_score(const float* __restrict__ ws, float* __restrict__ out)
{
  int b = threadIdx.x;
  if (b < BB) out[(size_t)BB*TT + b] = ws[BB + b] - ws[b];  // best - upto
}

extern "C" void kernel_launch(void* const* d_in, const int* in_sizes, int n_in,
                              void* d_out, int out_size, void* d_ws, size_t ws_size,
                              hipStream_t stream) {
  const float* em  = (const float*)d_in[0];
  const float* tr  = (const float*)d_in[1];
  const int*   ln  = (const int*)d_in[2];
  float* out = (float*)d_out;
  float* ws  = (float*)d_ws;
  viterbi_fwd<<<dim3(64), dim3(256), 0, stream>>>(em, tr, ln, out, ws);
  viterbi_score<<<dim3(1), dim3(64), 0, stream>>>(ws, out);
}